// Round 28
// baseline (221.874 us; speedup 1.0000x reference)
//
#include <hip/hip_runtime.h>
#include <hip/hip_bf16.h>

#define NN   50000
#define EE   600000
#define DINK 518
#define KP1  576          // padded K for encoder GEMM1 (9*64)
#define DD   128
#define NEG_SLOPE 0.2f
#define CAP  64           // bucket capacity per node (deg ~ Poisson(12); P(>64)~1e-24)
#define PREPB 770         // prep blocks; blocks >= PREPB do bucket work

typedef short bf16x8 __attribute__((ext_vector_type(8)));
typedef float f32x4 __attribute__((ext_vector_type(4)));

typedef const __attribute__((address_space(1))) void* gp1_t;
typedef __attribute__((address_space(3))) void* lp3_t;

__device__ __forceinline__ void load_lds16(const void* g, void* l) {
  __builtin_amdgcn_global_load_lds((gp1_t)g, (lp3_t)l, 16, 0, 0);
}

__device__ __forceinline__ unsigned short f2bf(float f) {
  union { float f; unsigned u; } q; q.f = f;
  unsigned u = q.u + 0x7FFFu + ((q.u >> 16) & 1u);   // RNE
  return (unsigned short)(u >> 16);
}
__device__ __forceinline__ float bflo(unsigned u) {
  union { unsigned u; float f; } q; q.u = u << 16; return q.f;
}
__device__ __forceinline__ float bfhi(unsigned u) {
  union { unsigned u; float f; } q; q.u = u & 0xFFFF0000u; return q.f;
}

// ---------------- bf16 MFMA GEMM (layer 2):  C = A @ BT^T, DOTS epilogue ----
// LDS tiles XOR-source-swizzled (round 25: conflicts 8.1M -> 0, verified).
template<bool OUT_BF16, bool RELU, bool HASBIAS, bool DOTS>
__global__ __launch_bounds__(256) void gemm_mfma(
    const unsigned short* __restrict__ A, const unsigned short* __restrict__ BT,
    const float* __restrict__ bias, void* __restrict__ Cout,
    int M, int Ncols, int K,
    const float* __restrict__ att_src, const float* __restrict__ att_dst,
    float* __restrict__ ssrc, float* __restrict__ sdst) {
  __shared__ short As[128][64];
  __shared__ short Bs[128][64];
  __shared__ float sp[128], dp[128];
  const int tid = threadIdx.x;
  const int lane = tid & 63;
  const int wid = tid >> 6;
  const int wr = wid >> 1, wc = wid & 1;
  const int bm = blockIdx.x * 128;
  const int bn = blockIdx.y * 128;
  const int ar = tid >> 3;
  const int ac = (tid & 7) * 8;

  f32x4 acc[4][4] = {};

  for (int k0 = 0; k0 < K; k0 += 64) {
#pragma unroll
    for (int i = 0; i < 4; i++) {
      int row = ar + i * 32;
      int acs = ac ^ ((row & 7) << 3);   // pre-swizzled source col (shorts)
      load_lds16(A + (size_t)(bm + row) * K + k0 + acs, &As[row][ac]);
    }
#pragma unroll
    for (int i = 0; i < 4; i++) {
      int row = ar + i * 32;
      int acs = ac ^ ((row & 7) << 3);
      load_lds16(BT + (size_t)(bn + row) * K + k0 + acs, &Bs[row][ac]);
    }
    __syncthreads();
#pragma unroll
    for (int ks = 0; ks < 2; ks++) {
      bf16x8 af[4], bfm[4];
#pragma unroll
      for (int f = 0; f < 4; f++) {
        int ra = wr * 64 + f * 16 + (lane & 15);
        af[f] = *(const bf16x8*)&As[ra][(ks * 32 + (lane >> 4) * 8) ^ ((ra & 7) << 3)];
      }
#pragma unroll
      for (int f = 0; f < 4; f++) {
        int rb = wc * 64 + f * 16 + (lane & 15);
        bfm[f] = *(const bf16x8*)&Bs[rb][(ks * 32 + (lane >> 4) * 8) ^ ((rb & 7) << 3)];
      }
#pragma unroll
      for (int i = 0; i < 4; i++)
#pragma unroll
        for (int j = 0; j < 4; j++)
          acc[i][j] = __builtin_amdgcn_mfma_f32_16x16x32_bf16(af[i], bfm[j], acc[i][j], 0, 0, 0);
    }
    __syncthreads();
  }

  // C/D layout (m89/m91): col = lane&15, row = (lane>>4)*4 + reg
  const int col0 = bn + wc * 64 + (lane & 15);
  const int row0 = bm + wr * 64 + (lane >> 4) * 4;
#pragma unroll
  for (int i = 0; i < 4; i++) {
#pragma unroll
    for (int jf = 0; jf < 4; jf++) {
      int col = col0 + jf * 16;
      float bv = HASBIAS ? bias[col] : 0.f;
#pragma unroll
      for (int j = 0; j < 4; j++) {
        int row = row0 + i * 16 + j;
        if (row < M) {
          float v = acc[i][jf][j] + bv;
          if (RELU) v = fmaxf(v, 0.f);
          if (OUT_BF16)
            ((unsigned short*)Cout)[(size_t)row * Ncols + col] = f2bf(v);
          else
            ((float*)Cout)[(size_t)row * Ncols + col] = v;
        }
      }
    }
  }

  if (DOTS) {
    float as_[4], ad_[4], bv_[4];
#pragma unroll
    for (int jf = 0; jf < 4; jf++) {
      int col = col0 + jf * 16;           // bn==0, covers 0..127 across wc
      as_[jf] = att_src[col];
      ad_[jf] = att_dst[col];
      bv_[jf] = HASBIAS ? bias[col] : 0.f;
    }
    float ps[4][4], pd[4][4];
#pragma unroll
    for (int i = 0; i < 4; i++) {
#pragma unroll
      for (int j = 0; j < 4; j++) {
        float s = 0.f, d = 0.f;
#pragma unroll
        for (int jf = 0; jf < 4; jf++) {
          float vv = acc[i][jf][j] + bv_[jf];
          s += vv * as_[jf];
          d += vv * ad_[jf];
        }
#pragma unroll
        for (int off = 1; off < 16; off <<= 1) {   // butterfly over lane&15 (cols)
          s += __shfl_xor(s, off);
          d += __shfl_xor(d, off);
        }
        ps[i][j] = s; pd[i][j] = d;
      }
    }
    // cross-wave (wc) combine via LDS; local row = wr*64 + i*16 + (lane>>4)*4 + j
    if (wc == 0 && (lane & 15) == 0) {
#pragma unroll
      for (int i = 0; i < 4; i++)
#pragma unroll
        for (int j = 0; j < 4; j++) {
          int r = wr * 64 + i * 16 + (lane >> 4) * 4 + j;
          sp[r] = ps[i][j]; dp[r] = pd[i][j];
        }
    }
    __syncthreads();
    if (wc == 1 && (lane & 15) == 0) {
#pragma unroll
      for (int i = 0; i < 4; i++)
#pragma unroll
        for (int j = 0; j < 4; j++) {
          int r = wr * 64 + i * 16 + (lane >> 4) * 4 + j;
          sp[r] += ps[i][j]; dp[r] += pd[i][j];
        }
    }
    __syncthreads();
    if (tid < 128) {
      int gr = bm + tid;
      if (gr < M) { ssrc[gr] = sp[tid]; sdst[gr] = dp[tid]; }
    }
  }
}

// -------- fused encoder: hp = relu(x@W1+b1) @ W2L1 + b2l1, + DOTS -----------
// Pure encoder again (round 26 form, 74us measured); bucket work moved into
// prep_kernel's occupancy shadow (round 27's in-kernel tail cost +16us).
__global__ __launch_bounds__(256) void enc_fused(
    const float* __restrict__ x, const unsigned short* __restrict__ W1T,
    const float* __restrict__ b1, const unsigned short* __restrict__ W2L1T,
    const float* __restrict__ b2l1,
    const float* __restrict__ att_src, const float* __restrict__ att_dst,
    unsigned short* __restrict__ hp, float* __restrict__ ssrc,
    float* __restrict__ sdst) {
  __shared__ short As[64][68];
  __shared__ short Bs[256][64];
  __shared__ short midT[64][264];
  __shared__ float sp4[4][64], dp4[4][64];
  const int tid = threadIdx.x;
  const int lane = tid & 63;
  const int wid = tid >> 6;
  const int bm = blockIdx.x * 64;
  const int br = tid >> 3;              // loader row 0..31
  const int bc = (tid & 7) * 8;
  const int rlane = lane >> 5;
  const int klane = (lane & 31) * 2;

  // ---- phase 1: mid = relu(x @ W1T + b1), tile [64][256] ----
  f32x4 acc[4][4] = {};
  for (int k0 = 0; k0 < KP1; k0 += 64) {
#pragma unroll
    for (int i = 0; i < 8; i++)
      load_lds16(W1T + (size_t)(br + i * 32) * KP1 + k0 + bc, &Bs[br + i * 32][bc]);
    float2 v[8];
    const int kk = k0 + klane;
    const bool kok = (kk < DINK);
#pragma unroll
    for (int i = 0; i < 8; i++) {
      int grow = bm + wid * 16 + i * 2 + rlane;
      v[i] = make_float2(0.f, 0.f);
      if (kok && grow < NN) v[i] = *(const float2*)&x[(size_t)grow * DINK + kk];
    }
#pragma unroll
    for (int i = 0; i < 8; i++) {
      int rl = wid * 16 + i * 2 + rlane;
      unsigned pk;
      asm("v_cvt_pk_bf16_f32 %0, %1, %2" : "=v"(pk) : "v"(v[i].x), "v"(v[i].y));
      *(unsigned*)&As[rl][klane] = pk;
    }
    __syncthreads();
#pragma unroll
    for (int ks = 0; ks < 2; ks++) {
      bf16x8 af[4], bfm[4];
#pragma unroll
      for (int f = 0; f < 4; f++)
        af[f] = *(const bf16x8*)&As[f * 16 + (lane & 15)][ks * 32 + (lane >> 4) * 8];
#pragma unroll
      for (int c = 0; c < 4; c++)
        bfm[c] = *(const bf16x8*)&Bs[wid * 64 + c * 16 + (lane & 15)][ks * 32 + (lane >> 4) * 8];
#pragma unroll
      for (int f = 0; f < 4; f++)
#pragma unroll
        for (int c = 0; c < 4; c++)
          acc[f][c] = __builtin_amdgcn_mfma_f32_16x16x32_bf16(af[f], bfm[c], acc[f][c], 0, 0, 0);
    }
    __syncthreads();
  }
  // epilogue 1: relu + bias -> midT (LDS bf16; same rounding as old global mid)
  {
    const int col0 = wid * 64 + (lane & 15);
    const int r0 = (lane >> 4) * 4;
#pragma unroll
    for (int c = 0; c < 4; c++) {
      int col = col0 + c * 16;
      float bv = b1[col];
#pragma unroll
      for (int f = 0; f < 4; f++)
#pragma unroll
        for (int j = 0; j < 4; j++) {
          float vv = fmaxf(acc[f][c][j] + bv, 0.f);
          midT[f * 16 + r0 + j][col] = (short)f2bf(vv);
        }
    }
  }
  __syncthreads();

  // ---- phase 2: hp = midT @ W2L1T^T + b2l1 ----
  f32x4 acc2[4][2] = {};
  for (int t2 = 0; t2 < 4; ++t2) {
    const int k0 = t2 * 64;
#pragma unroll
    for (int i = 0; i < 4; i++)
      load_lds16(W2L1T + (size_t)(br + i * 32) * 256 + k0 + bc, &Bs[br + i * 32][bc]);
    __syncthreads();
#pragma unroll
    for (int ks = 0; ks < 2; ks++) {
      bf16x8 af[4], bfm[2];
#pragma unroll
      for (int f = 0; f < 4; f++)
        af[f] = *(const bf16x8*)&midT[f * 16 + (lane & 15)][k0 + ks * 32 + (lane >> 4) * 8];
#pragma unroll
      for (int cf = 0; cf < 2; cf++)
        bfm[cf] = *(const bf16x8*)&Bs[wid * 32 + cf * 16 + (lane & 15)][ks * 32 + (lane >> 4) * 8];
#pragma unroll
      for (int f = 0; f < 4; f++)
#pragma unroll
        for (int cf = 0; cf < 2; cf++)
          acc2[f][cf] = __builtin_amdgcn_mfma_f32_16x16x32_bf16(af[f], bfm[cf], acc2[f][cf], 0, 0, 0);
    }
    __syncthreads();
  }
  // epilogue 2: hp write + DOTS (butterfly over lane&15, 4-wave LDS combine)
  {
    const int col0 = wid * 32 + (lane & 15);
    const int r0 = (lane >> 4) * 4;
    float as_[2], ad_[2], bv_[2];
#pragma unroll
    for (int cf = 0; cf < 2; cf++) {
      int col = col0 + cf * 16;
      as_[cf] = att_src[col]; ad_[cf] = att_dst[col]; bv_[cf] = b2l1[col];
    }
#pragma unroll
    for (int f = 0; f < 4; f++) {
#pragma unroll
      for (int j = 0; j < 4; j++) {
        int row = bm + f * 16 + r0 + j;
        float s = 0.f, d = 0.f;
#pragma unroll
        for (int cf = 0; cf < 2; cf++) {
          float vv = acc2[f][cf][j] + bv_[cf];
          s += vv * as_[cf]; d += vv * ad_[cf];
          if (row < NN)
            hp[(size_t)row * DD + col0 + cf * 16] = f2bf(vv);
        }
#pragma unroll
        for (int off = 1; off < 16; off <<= 1) {
          s += __shfl_xor(s, off);
          d += __shfl_xor(d, off);
        }
        if ((lane & 15) == 0) {
          sp4[wid][f * 16 + r0 + j] = s;
          dp4[wid][f * 16 + r0 + j] = d;
        }
      }
    }
  }
  __syncthreads();
  if (tid < 64) {
    int gr = bm + tid;
    if (gr < NN) {
      ssrc[gr] = sp4[0][tid] + sp4[1][tid] + sp4[2][tid] + sp4[3][tid];
      sdst[gr] = dp4[0][tid] + dp4[1][tid] + dp4[2][tid] + dp4[3][tid];
    }
  }
}

// -------- combined weight prep + bucket CSR build ---------------------------
// Blocks >= PREPB run the bucket scatter (one edge/thread), overlapping the
// light transpose blocks. cnt/g are zeroed by hipMemsetAsync BEFORE this
// kernel (same stream -> ordered), so no intra-kernel ordering dependence.
__device__ __forceinline__ void convT_body(const float* __restrict__ W,
                                           unsigned short* __restrict__ WT,
                                           int K, int Ncols, int Kpad, int t) {
  int n = t / Kpad, k = t % Kpad;
  float v = (k < K) ? W[(size_t)k * Ncols + n] : 0.f;
  WT[(size_t)n * Kpad + k] = f2bf(v);
}

__global__ __launch_bounds__(256) void prep_kernel(
    const float* __restrict__ W1, const float* __restrict__ W2,
    const float* __restrict__ l1, const float* __restrict__ l2,
    const float* __restrict__ le1, const float* __restrict__ le2,
    const float* __restrict__ ae1, const float* __restrict__ ae2,
    const float* __restrict__ rel_emb, const float* __restrict__ b2,
    unsigned short* __restrict__ W1T, unsigned short* __restrict__ W2L1T,
    unsigned short* __restrict__ l2T, float* __restrict__ tables,
    float* __restrict__ b2l1,
    const int* __restrict__ srcv, const int* __restrict__ dstv,
    const int* __restrict__ eattr, int* __restrict__ cnt,
    int* __restrict__ cpack) {
  const int b = blockIdx.x, tid = threadIdx.x;
  if (b >= PREPB) {
    // ---- bucket build blocks ----
    int e = (b - PREPB) * 256 + tid;
    if (e < EE) {
      int d = dstv[e];
      int p = atomicAdd(&cnt[d], 1);
      if (p < CAP) cpack[d * CAP + p] = (srcv[e] << 5) | eattr[e];
    }
    return;
  }
  if (b < 576) { convT_body(W1, W1T, DINK, 256, KP1, b * 256 + tid); return; }
  if (b < 640) { convT_body(l2, l2T, 128, 128, 128, (b - 576) * 256 + tid); return; }
  if (b < 642) {
    // tables[layer][r] = rel_emb[r] . (line @ att_edge)
    const int layer = b - 640;
    const float* line = layer ? le2 : le1;
    const float* ae   = layer ? ae2 : ae1;
    __shared__ float ve[32];
    if (tid < 32) {
      float s = 0.f;
      for (int d = 0; d < 128; d++) s += line[tid * 128 + d] * ae[d];
      ve[tid] = s;
    }
    __syncthreads();
    if (tid < 26) {
      float s = 0.f;
      for (int j = 0; j < 32; j++) s += rel_emb[tid * 32 + j] * ve[j];
      tables[layer * 32 + tid] = s;
    }
    return;
  }
  {
    // b in [642, 770): W2L1T[n][k] = sum_j W2[k][j]*lin1[j][n]
    const int n = b - 642;
    __shared__ float lc[128];
    if (tid < 128) lc[tid] = l1[(size_t)tid * 128 + n];
    __syncthreads();
    float s = 0.f;
    const float* wrow = W2 + (size_t)tid * 128;
    for (int j = 0; j < 128; j++) s += wrow[j] * lc[j];
    W2L1T[(size_t)n * 256 + tid] = f2bf(s);
    if (tid == 0) {
      float bb = 0.f;
      for (int j = 0; j < 128; j++) bb += b2[j] * lc[j];
      b2l1[n] = bb;
    }
  }
}

// ---------------- fused GAT aggregate: TWO NODES PER WAVE -------------------
__global__ __launch_bounds__(256) void gat_gather_kernel(
    const int* __restrict__ cnt, const int* __restrict__ cpack,
    const float* __restrict__ table,
    const float* __restrict__ ssrc, const float* __restrict__ sdst,
    const unsigned short* __restrict__ hp, const float* __restrict__ bias,
    unsigned short* __restrict__ hout, int n) {
  __shared__ float exs[4][2][CAP];
  __shared__ int   srcs[4][2][CAP];
  const int wid = threadIdx.x >> 6, lane = threadIdx.x & 63;
  const int half = lane >> 5, hlane = lane & 31;
  const int node = ((blockIdx.x * blockDim.x + threadIdx.x) >> 6) * 2 + half;
  const bool valid = node < n;
  int deg = valid ? cnt[node] : 0;
  if (deg > CAP) deg = CAP;   // impossible for this graph; guards OOB
  const int j0 = node * CAP;
  const float sd = valid ? sdst[node] : 0.f;
  float den = 0.f, esum = 0.f;
  for (int k = hlane; k < deg; k += 32) {   // deg <= 64: at most 2 steps
    int pk_ = cpack[j0 + k];
    int s = pk_ >> 5;
    float t = table[pk_ & 31];
    float l = ssrc[s] + sd + t;
    l = (l > 0.f) ? l : NEG_SLOPE * l;
    float ex = expf(l);
    exs[wid][half][k] = ex; srcs[wid][half][k] = s * DD;
    den += ex; esum += t;
  }
#pragma unroll
  for (int off = 16; off; off >>= 1) {   // within-half butterfly
    den += __shfl_xor(den, off);
    esum += __shfl_xor(esum, off);
  }
  // self-loop (edge vector = mean of incoming -> table-space mean)
  float tl = esum / fmaxf((float)deg, 1.f);
  float ll = (valid ? ssrc[node] : 0.f) + sd + tl;
  ll = (ll > 0.f) ? ll : NEG_SLOPE * ll;
  float exl = expf(ll);
  den += exl;
  const float inv = 1.f / (den + 1e-16f);
  // pass 2: lane owns cols c..c+3 (one 8B uint2 of bf16 per row)
  const int c = hlane * 4;
  float a0, a1, a2, a3;
  {
    uint2 w = valid ? *(const uint2*)&hp[(size_t)node * DD + c] : make_uint2(0, 0);
    float a = exl * inv;
    a0 = a * bflo(w.x); a1 = a * bfhi(w.x);
    a2 = a * bflo(w.y); a3 = a * bfhi(w.y);
  }
  int k = 0;
  for (; k + 8 <= deg; k += 8) {
    uint2 w[8]; float a[8];
#pragma unroll
    for (int q = 0; q < 8; q++) {
      a[q] = exs[wid][half][k + q] * inv;
      w[q] = *(const uint2*)&hp[(size_t)(srcs[wid][half][k + q] + c)];
    }
#pragma unroll
    for (int q = 0; q < 8; q++) {
      a0 += a[q] * bflo(w[q].x); a1 += a[q] * bfhi(w[q].x);
      a2 += a[q] * bflo(w[q].y); a3 += a[q] * bfhi(w[q].y);
    }
  }
  for (; k + 4 <= deg; k += 4) {
    uint2 w[4]; float a[4];
#pragma unroll
    for (int q = 0; q < 4; q++) {
      a[q] = exs[wid][half][k + q] * inv;
      w[q] = *(const uint2*)&hp[(size_t)(srcs[wid][half][k + q] + c)];
    }
#pragma unroll
    for (int q = 0; q < 4; q++) {
      a0 += a[q] * bflo(w[q].x); a1 += a[q] * bfhi(w[q].x);
      a2 += a[q] * bflo(w[q].y); a3 += a[q] * bfhi(w[q].y);
    }
  }
  for (; k < deg; k++) {
    float aq = exs[wid][half][k] * inv;
    uint2 w = *(const uint2*)&hp[(size_t)(srcs[wid][half][k] + c)];
    a0 += aq * bflo(w.x); a1 += aq * bfhi(w.x);
    a2 += aq * bflo(w.y); a3 += aq * bfhi(w.y);
  }
  if (valid) {
    a0 = fmaxf(a0 + bias[c], 0.f);
    a1 = fmaxf(a1 + bias[c + 1], 0.f);
    a2 = fmaxf(a2 + bias[c + 2], 0.f);
    a3 = fmaxf(a3 + bias[c + 3], 0.f);
    uint2 o;
    o.x = (unsigned)f2bf(a0) | ((unsigned)f2bf(a1) << 16);
    o.y = (unsigned)f2bf(a2) | ((unsigned)f2bf(a3) << 16);
    *(uint2*)&hout[(size_t)node * DD + c] = o;
  }
}

__global__ void pool_kernel(const unsigned short* __restrict__ h, float* __restrict__ g, int n) {
  __shared__ float sh[128];
  int tid = threadIdx.x;
  int cp = tid & 63, half = tid >> 6;     // 4 row-groups, lane owns 2 cols
  float sx = 0.f, sy = 0.f;
  for (int r = blockIdx.x * 4 + half; r < n; r += gridDim.x * 4) {
    unsigned w = *(const unsigned*)&h[(size_t)r * DD + cp * 2];
    sx += bflo(w); sy += bfhi(w);
  }
  if (half == 0) { sh[cp * 2] = sx; sh[cp * 2 + 1] = sy; }
  __syncthreads();
  if (half == 1) { sh[cp * 2] += sx; sh[cp * 2 + 1] += sy; }
  __syncthreads();
  if (half == 2) { sh[cp * 2] += sx; sh[cp * 2 + 1] += sy; }
  __syncthreads();
  if (half == 3) {
    atomicAdd(&g[cp * 2], sh[cp * 2] + sx);
    atomicAdd(&g[cp * 2 + 1], sh[cp * 2 + 1] + sy);
  }
}

__global__ void readout_kernel(const float* __restrict__ g, const float* __restrict__ Wr1,
                               const float* __restrict__ br1, const float* __restrict__ Wr2,
                               const float* __restrict__ br2, float* __restrict__ out,
                               float inv_n) {
  __shared__ float gl[128];
  __shared__ float m[64];
  int t = threadIdx.x;  // 64 threads
  gl[t] = g[t] * inv_n;
  gl[t + 64] = g[t + 64] * inv_n;
  __syncthreads();
  {
    float acc = br1[t];
    for (int c = 0; c < 128; c++) acc += gl[c] * Wr1[c * 64 + t];
    m[t] = fmaxf(acc, 0.f);
  }
  __syncthreads();
  if (t < 32) {
    float acc = br2[t];
    for (int j = 0; j < 64; j++) acc += m[j] * Wr2[j * 32 + t];
    out[t] = acc;
  }
}

// ---------------- launch ----------------
extern "C" void kernel_launch(void* const* d_in, const int* in_sizes, int n_in,
                              void* d_out, int out_size, void* d_ws, size_t ws_size,
                              hipStream_t stream) {
  const float* x     = (const float*)d_in[0];
  const int*   ei    = (const int*)d_in[1];
  const int*   eattr = (const int*)d_in[2];
  const float* W1 = (const float*)d_in[3];
  const float* b1 = (const float*)d_in[4];
  const float* W2 = (const float*)d_in[5];
  const float* b2 = (const float*)d_in[6];
  const float* rel_emb = (const float*)d_in[7];
  const float* lin[2]      = {(const float*)d_in[8],  (const float*)d_in[14]};
  const float* att_src[2]  = {(const float*)d_in[9],  (const float*)d_in[15]};
  const float* att_dst[2]  = {(const float*)d_in[10], (const float*)d_in[16]};
  const float* att_edge[2] = {(const float*)d_in[11], (const float*)d_in[17]};
  const float* line[2]     = {(const float*)d_in[12], (const float*)d_in[18]};
  const float* bias[2]     = {(const float*)d_in[13], (const float*)d_in[19]};
  const float* Wr1 = (const float*)d_in[20];
  const float* br1 = (const float*)d_in[21];
  const float* Wr2 = (const float*)d_in[22];
  const float* br2 = (const float*)d_in[23];
  float* out = (float*)d_out;

  const int* srcv = ei;
  const int* dstv = ei + EE;

  char* wsb = (char*)d_ws;
  unsigned short* hA  = (unsigned short*)(wsb + 0);
  unsigned short* hp  = (unsigned short*)(wsb + 12900000);
  unsigned short* hB  = (unsigned short*)(wsb + 25900000);
  unsigned short* W1T   = (unsigned short*)(wsb + 64600000);
  unsigned short* W2L1T = (unsigned short*)(wsb + 64900000);   // [128][256] bf16
  unsigned short* lin2T = (unsigned short*)(wsb + 65040000);
  int* cnt     = (int*)(wsb + 65300008);                       // [50000]
  float* ssrc  = (float*)(wsb + 68100008);
  float* sdst  = (float*)(wsb + 68300008);
  float* tables = (float*)(wsb + 68502056);   // [2][32]
  float* g      = (float*)(wsb + 68502312);   // 128 f32
  float* b2l1   = (float*)(wsb + 68502824);   // 128 f32
  int* cpack    = (int*)(wsb + 70000000);     // [50000][64] = 12.8 MB

  dim3 blk(256);
  const int BKB = (EE + 255) / 256;   // 2344 bucket blocks

  // zero cnt + g BEFORE prep (same stream -> ordered before bucket blocks)
  hipMemsetAsync(cnt, 0, NN * sizeof(int), stream);
  hipMemsetAsync(g, 0, 128 * sizeof(float), stream);

  // prep (weight transposes + tables + W2L1) + bucket CSR blocks overlapped
  prep_kernel<<<dim3(PREPB + BKB), blk, 0, stream>>>(
      W1, W2, lin[0], lin[1], line[0], line[1], att_edge[0], att_edge[1],
      rel_emb, b2, W1T, W2L1T, lin2T, tables, b2l1,
      srcv, dstv, eattr, cnt, cpack);

  // fused encoder+layer1-lin: hp + ssrc/sdst directly from x
  enc_fused<<<dim3(782), blk, 0, stream>>>(
      x, W1T, b1, W2L1T, b2l1, att_src[0], att_dst[0], hp, ssrc, sdst);

  // layer 1 gather: hp -> hB
  gat_gather_kernel<<<dim3((NN / 2 * 64 + 255) / 256), blk, 0, stream>>>(
      cnt, cpack, tables, ssrc, sdst, hp, bias[0], hB, NN);
  // layer 2: hB -> (lin2+DOTS) hp,ssrc,sdst -> (gather) hA
  gemm_mfma<true, false, false, true><<<dim3(391, 1), blk, 0, stream>>>(
      hB, lin2T, nullptr, hp, NN, 128, 128, att_src[1], att_dst[1], ssrc, sdst);
  gat_gather_kernel<<<dim3((NN / 2 * 64 + 255) / 256), blk, 0, stream>>>(
      cnt, cpack, tables + 32, ssrc, sdst, hp, bias[1], hA, NN);

  pool_kernel<<<dim3(256), blk, 0, stream>>>(hA, g, NN);
  readout_kernel<<<1, 64, 0, stream>>>(g, Wr1, br1, Wr2, br2, out, 1.0f / NN);
}

// Round 29
// 183.520 us; speedup vs baseline: 1.2090x; 1.2090x over previous
//
#include <hip/hip_runtime.h>
#include <hip/hip_bf16.h>

#define NN   50000
#define EE   600000
#define DINK 518
#define KP1  576          // padded K for encoder GEMM1 (9*64)
#define DD   128
#define NEG_SLOPE 0.2f
#define CAP  64           // bucket capacity per node (deg ~ Poisson(12); P(>64)~1e-24)
#define ENCB 782          // encoder blocks; blocks >= ENCB do bucket work

typedef short bf16x8 __attribute__((ext_vector_type(8)));
typedef float f32x4 __attribute__((ext_vector_type(4)));

typedef const __attribute__((address_space(1))) void* gp1_t;
typedef __attribute__((address_space(3))) void* lp3_t;

__device__ __forceinline__ void load_lds16(const void* g, void* l) {
  __builtin_amdgcn_global_load_lds((gp1_t)g, (lp3_t)l, 16, 0, 0);
}

__device__ __forceinline__ unsigned short f2bf(float f) {
  union { float f; unsigned u; } q; q.f = f;
  unsigned u = q.u + 0x7FFFu + ((q.u >> 16) & 1u);   // RNE
  return (unsigned short)(u >> 16);
}
__device__ __forceinline__ float bflo(unsigned u) {
  union { unsigned u; float f; } q; q.u = u << 16; return q.f;
}
__device__ __forceinline__ float bfhi(unsigned u) {
  union { unsigned u; float f; } q; q.u = u & 0xFFFF0000u; return q.f;
}

// ---------------- bf16 MFMA GEMM (layer 2):  C = A @ BT^T, DOTS epilogue ----
// LDS tiles XOR-source-swizzled (round 25: conflicts 8.1M -> 0, verified).
template<bool OUT_BF16, bool RELU, bool HASBIAS, bool DOTS>
__global__ __launch_bounds__(256) void gemm_mfma(
    const unsigned short* __restrict__ A, const unsigned short* __restrict__ BT,
    const float* __restrict__ bias, void* __restrict__ Cout,
    int M, int Ncols, int K,
    const float* __restrict__ att_src, const float* __restrict__ att_dst,
    float* __restrict__ ssrc, float* __restrict__ sdst) {
  __shared__ short As[128][64];
  __shared__ short Bs[128][64];
  __shared__ float sp[128], dp[128];
  const int tid = threadIdx.x;
  const int lane = tid & 63;
  const int wid = tid >> 6;
  const int wr = wid >> 1, wc = wid & 1;
  const int bm = blockIdx.x * 128;
  const int bn = blockIdx.y * 128;
  const int ar = tid >> 3;
  const int ac = (tid & 7) * 8;

  f32x4 acc[4][4] = {};

  for (int k0 = 0; k0 < K; k0 += 64) {
#pragma unroll
    for (int i = 0; i < 4; i++) {
      int row = ar + i * 32;
      int acs = ac ^ ((row & 7) << 3);   // pre-swizzled source col (shorts)
      load_lds16(A + (size_t)(bm + row) * K + k0 + acs, &As[row][ac]);
    }
#pragma unroll
    for (int i = 0; i < 4; i++) {
      int row = ar + i * 32;
      int acs = ac ^ ((row & 7) << 3);
      load_lds16(BT + (size_t)(bn + row) * K + k0 + acs, &Bs[row][ac]);
    }
    __syncthreads();
#pragma unroll
    for (int ks = 0; ks < 2; ks++) {
      bf16x8 af[4], bfm[4];
#pragma unroll
      for (int f = 0; f < 4; f++) {
        int ra = wr * 64 + f * 16 + (lane & 15);
        af[f] = *(const bf16x8*)&As[ra][(ks * 32 + (lane >> 4) * 8) ^ ((ra & 7) << 3)];
      }
#pragma unroll
      for (int f = 0; f < 4; f++) {
        int rb = wc * 64 + f * 16 + (lane & 15);
        bfm[f] = *(const bf16x8*)&Bs[rb][(ks * 32 + (lane >> 4) * 8) ^ ((rb & 7) << 3)];
      }
#pragma unroll
      for (int i = 0; i < 4; i++)
#pragma unroll
        for (int j = 0; j < 4; j++)
          acc[i][j] = __builtin_amdgcn_mfma_f32_16x16x32_bf16(af[i], bfm[j], acc[i][j], 0, 0, 0);
    }
    __syncthreads();
  }

  // C/D layout (m89/m91): col = lane&15, row = (lane>>4)*4 + reg
  const int col0 = bn + wc * 64 + (lane & 15);
  const int row0 = bm + wr * 64 + (lane >> 4) * 4;
#pragma unroll
  for (int i = 0; i < 4; i++) {
#pragma unroll
    for (int jf = 0; jf < 4; jf++) {
      int col = col0 + jf * 16;
      float bv = HASBIAS ? bias[col] : 0.f;
#pragma unroll
      for (int j = 0; j < 4; j++) {
        int row = row0 + i * 16 + j;
        if (row < M) {
          float v = acc[i][jf][j] + bv;
          if (RELU) v = fmaxf(v, 0.f);
          if (OUT_BF16)
            ((unsigned short*)Cout)[(size_t)row * Ncols + col] = f2bf(v);
          else
            ((float*)Cout)[(size_t)row * Ncols + col] = v;
        }
      }
    }
  }

  if (DOTS) {
    float as_[4], ad_[4], bv_[4];
#pragma unroll
    for (int jf = 0; jf < 4; jf++) {
      int col = col0 + jf * 16;           // bn==0, covers 0..127 across wc
      as_[jf] = att_src[col];
      ad_[jf] = att_dst[col];
      bv_[jf] = HASBIAS ? bias[col] : 0.f;
    }
    float ps[4][4], pd[4][4];
#pragma unroll
    for (int i = 0; i < 4; i++) {
#pragma unroll
      for (int j = 0; j < 4; j++) {
        float s = 0.f, d = 0.f;
#pragma unroll
        for (int jf = 0; jf < 4; jf++) {
          float vv = acc[i][jf][j] + bv_[jf];
          s += vv * as_[jf];
          d += vv * ad_[jf];
        }
#pragma unroll
        for (int off = 1; off < 16; off <<= 1) {   // butterfly over lane&15 (cols)
          s += __shfl_xor(s, off);
          d += __shfl_xor(d, off);
        }
        ps[i][j] = s; pd[i][j] = d;
      }
    }
    // cross-wave (wc) combine via LDS; local row = wr*64 + i*16 + (lane>>4)*4 + j
    if (wc == 0 && (lane & 15) == 0) {
#pragma unroll
      for (int i = 0; i < 4; i++)
#pragma unroll
        for (int j = 0; j < 4; j++) {
          int r = wr * 64 + i * 16 + (lane >> 4) * 4 + j;
          sp[r] = ps[i][j]; dp[r] = pd[i][j];
        }
    }
    __syncthreads();
    if (wc == 1 && (lane & 15) == 0) {
#pragma unroll
      for (int i = 0; i < 4; i++)
#pragma unroll
        for (int j = 0; j < 4; j++) {
          int r = wr * 64 + i * 16 + (lane >> 4) * 4 + j;
          sp[r] += ps[i][j]; dp[r] += pd[i][j];
        }
    }
    __syncthreads();
    if (tid < 128) {
      int gr = bm + tid;
      if (gr < M) { ssrc[gr] = sp[tid]; sdst[gr] = dp[tid]; }
    }
  }
}

// -------- fused encoder: hp = relu(x@W1+b1) @ W2L1 + b2l1, + DOTS -----------
// Blocks >= ENCB instead run the bucket CSR scatter (one edge per thread) —
// they backfill the CU slots left idle by the 2-block/CU encoder occupancy.
// (Round-28 experiment moved bucket to prep's shadow: -38us WORSE — the
// overlap partner must be the LONG kernel. This round-27 placement is best.)
__global__ __launch_bounds__(256) void enc_fused(
    const float* __restrict__ x, const unsigned short* __restrict__ W1T,
    const float* __restrict__ b1, const unsigned short* __restrict__ W2L1T,
    const float* __restrict__ b2l1,
    const float* __restrict__ att_src, const float* __restrict__ att_dst,
    unsigned short* __restrict__ hp, float* __restrict__ ssrc,
    float* __restrict__ sdst,
    const int* __restrict__ srcv, const int* __restrict__ dstv,
    const int* __restrict__ eattr, int* __restrict__ cnt,
    int* __restrict__ cpack) {
  if (blockIdx.x >= ENCB) {
    // ---- bucket build blocks ----
    int e = (blockIdx.x - ENCB) * 256 + threadIdx.x;
    if (e < EE) {
      int d = dstv[e];
      int p = atomicAdd(&cnt[d], 1);
      if (p < CAP) cpack[d * CAP + p] = (srcv[e] << 5) | eattr[e];
    }
    return;
  }
  __shared__ short As[64][68];
  __shared__ short Bs[256][64];
  __shared__ short midT[64][264];
  __shared__ float sp4[4][64], dp4[4][64];
  const int tid = threadIdx.x;
  const int lane = tid & 63;
  const int wid = tid >> 6;
  const int bm = blockIdx.x * 64;
  const int br = tid >> 3;              // loader row 0..31
  const int bc = (tid & 7) * 8;
  const int rlane = lane >> 5;
  const int klane = (lane & 31) * 2;

  // ---- phase 1: mid = relu(x @ W1T + b1), tile [64][256] ----
  f32x4 acc[4][4] = {};
  for (int k0 = 0; k0 < KP1; k0 += 64) {
#pragma unroll
    for (int i = 0; i < 8; i++)
      load_lds16(W1T + (size_t)(br + i * 32) * KP1 + k0 + bc, &Bs[br + i * 32][bc]);
    float2 v[8];
    const int kk = k0 + klane;
    const bool kok = (kk < DINK);
#pragma unroll
    for (int i = 0; i < 8; i++) {
      int grow = bm + wid * 16 + i * 2 + rlane;
      v[i] = make_float2(0.f, 0.f);
      if (kok && grow < NN) v[i] = *(const float2*)&x[(size_t)grow * DINK + kk];
    }
#pragma unroll
    for (int i = 0; i < 8; i++) {
      int rl = wid * 16 + i * 2 + rlane;
      unsigned pk;
      asm("v_cvt_pk_bf16_f32 %0, %1, %2" : "=v"(pk) : "v"(v[i].x), "v"(v[i].y));
      *(unsigned*)&As[rl][klane] = pk;
    }
    __syncthreads();
#pragma unroll
    for (int ks = 0; ks < 2; ks++) {
      bf16x8 af[4], bfm[4];
#pragma unroll
      for (int f = 0; f < 4; f++)
        af[f] = *(const bf16x8*)&As[f * 16 + (lane & 15)][ks * 32 + (lane >> 4) * 8];
#pragma unroll
      for (int c = 0; c < 4; c++)
        bfm[c] = *(const bf16x8*)&Bs[wid * 64 + c * 16 + (lane & 15)][ks * 32 + (lane >> 4) * 8];
#pragma unroll
      for (int f = 0; f < 4; f++)
#pragma unroll
        for (int c = 0; c < 4; c++)
          acc[f][c] = __builtin_amdgcn_mfma_f32_16x16x32_bf16(af[f], bfm[c], acc[f][c], 0, 0, 0);
    }
    __syncthreads();
  }
  // epilogue 1: relu + bias -> midT (LDS bf16; same rounding as old global mid)
  {
    const int col0 = wid * 64 + (lane & 15);
    const int r0 = (lane >> 4) * 4;
#pragma unroll
    for (int c = 0; c < 4; c++) {
      int col = col0 + c * 16;
      float bv = b1[col];
#pragma unroll
      for (int f = 0; f < 4; f++)
#pragma unroll
        for (int j = 0; j < 4; j++) {
          float vv = fmaxf(acc[f][c][j] + bv, 0.f);
          midT[f * 16 + r0 + j][col] = (short)f2bf(vv);
        }
    }
  }
  __syncthreads();

  // ---- phase 2: hp = midT @ W2L1T^T + b2l1 ----
  f32x4 acc2[4][2] = {};
  for (int t2 = 0; t2 < 4; ++t2) {
    const int k0 = t2 * 64;
#pragma unroll
    for (int i = 0; i < 4; i++)
      load_lds16(W2L1T + (size_t)(br + i * 32) * 256 + k0 + bc, &Bs[br + i * 32][bc]);
    __syncthreads();
#pragma unroll
    for (int ks = 0; ks < 2; ks++) {
      bf16x8 af[4], bfm[2];
#pragma unroll
      for (int f = 0; f < 4; f++)
        af[f] = *(const bf16x8*)&midT[f * 16 + (lane & 15)][k0 + ks * 32 + (lane >> 4) * 8];
#pragma unroll
      for (int cf = 0; cf < 2; cf++)
        bfm[cf] = *(const bf16x8*)&Bs[wid * 32 + cf * 16 + (lane & 15)][ks * 32 + (lane >> 4) * 8];
#pragma unroll
      for (int f = 0; f < 4; f++)
#pragma unroll
        for (int cf = 0; cf < 2; cf++)
          acc2[f][cf] = __builtin_amdgcn_mfma_f32_16x16x32_bf16(af[f], bfm[cf], acc2[f][cf], 0, 0, 0);
    }
    __syncthreads();
  }
  // epilogue 2: hp write + DOTS (butterfly over lane&15, 4-wave LDS combine)
  {
    const int col0 = wid * 32 + (lane & 15);
    const int r0 = (lane >> 4) * 4;
    float as_[2], ad_[2], bv_[2];
#pragma unroll
    for (int cf = 0; cf < 2; cf++) {
      int col = col0 + cf * 16;
      as_[cf] = att_src[col]; ad_[cf] = att_dst[col]; bv_[cf] = b2l1[col];
    }
#pragma unroll
    for (int f = 0; f < 4; f++) {
#pragma unroll
      for (int j = 0; j < 4; j++) {
        int row = bm + f * 16 + r0 + j;
        float s = 0.f, d = 0.f;
#pragma unroll
        for (int cf = 0; cf < 2; cf++) {
          float vv = acc2[f][cf][j] + bv_[cf];
          s += vv * as_[cf]; d += vv * ad_[cf];
          if (row < NN)
            hp[(size_t)row * DD + col0 + cf * 16] = f2bf(vv);
        }
#pragma unroll
        for (int off = 1; off < 16; off <<= 1) {
          s += __shfl_xor(s, off);
          d += __shfl_xor(d, off);
        }
        if ((lane & 15) == 0) {
          sp4[wid][f * 16 + r0 + j] = s;
          dp4[wid][f * 16 + r0 + j] = d;
        }
      }
    }
  }
  __syncthreads();
  if (tid < 64) {
    int gr = bm + tid;
    if (gr < NN) {
      ssrc[gr] = sp4[0][tid] + sp4[1][tid] + sp4[2][tid] + sp4[3][tid];
      sdst[gr] = dp4[0][tid] + dp4[1][tid] + dp4[2][tid] + dp4[3][tid];
    }
  }
}

// -------- combined weight prep: W1T, l2T, tables, W2L1 = W2@lin1, and -------
// -------- zeroing of cnt (bucket counters) + g (pool accumulator) -----------
__device__ __forceinline__ void convT_body(const float* __restrict__ W,
                                           unsigned short* __restrict__ WT,
                                           int K, int Ncols, int Kpad, int t) {
  int n = t / Kpad, k = t % Kpad;
  float v = (k < K) ? W[(size_t)k * Ncols + n] : 0.f;
  WT[(size_t)n * Kpad + k] = f2bf(v);
}

__global__ __launch_bounds__(256) void prep_kernel(
    const float* __restrict__ W1, const float* __restrict__ W2,
    const float* __restrict__ l1, const float* __restrict__ l2,
    const float* __restrict__ le1, const float* __restrict__ le2,
    const float* __restrict__ ae1, const float* __restrict__ ae2,
    const float* __restrict__ rel_emb, const float* __restrict__ b2,
    unsigned short* __restrict__ W1T, unsigned short* __restrict__ W2L1T,
    unsigned short* __restrict__ l2T, float* __restrict__ tables,
    float* __restrict__ b2l1, int* __restrict__ cnt, float* __restrict__ g) {
  const int b = blockIdx.x, tid = threadIdx.x;
  if (b < 576) { convT_body(W1, W1T, DINK, 256, KP1, b * 256 + tid); return; }
  if (b < 640) { convT_body(l2, l2T, 128, 128, 128, (b - 576) * 256 + tid); return; }
  if (b < 642) {
    // tables[layer][r] = rel_emb[r] . (line @ att_edge)
    const int layer = b - 640;
    const float* line = layer ? le2 : le1;
    const float* ae   = layer ? ae2 : ae1;
    __shared__ float ve[32];
    if (tid < 32) {
      float s = 0.f;
      for (int d = 0; d < 128; d++) s += line[tid * 128 + d] * ae[d];
      ve[tid] = s;
    }
    __syncthreads();
    if (tid < 26) {
      float s = 0.f;
      for (int j = 0; j < 32; j++) s += rel_emb[tid * 32 + j] * ve[j];
      tables[layer * 32 + tid] = s;
    }
    return;
  }
  if (b < 770) {
    // W2L1T[n][k] = sum_j W2[k][j]*lin1[j][n]  (n = output col, k = 0..255)
    const int n = b - 642;
    __shared__ float lc[128];
    if (tid < 128) lc[tid] = l1[(size_t)tid * 128 + n];
    __syncthreads();
    float s = 0.f;
    const float* wrow = W2 + (size_t)tid * 128;
    for (int j = 0; j < 128; j++) s += wrow[j] * lc[j];
    W2L1T[(size_t)n * 256 + tid] = f2bf(s);
    if (tid == 0) {
      float bb = 0.f;
      for (int j = 0; j < 128; j++) bb += b2[j] * lc[j];
      b2l1[n] = bb;
    }
    return;
  }
  // b in [770, 966): zero cnt[50000]; block 770 also zeros g[128]
  {
    const int zb = b - 770;
    int i = zb * 256 + tid;
    if (i < NN) cnt[i] = 0;
    if (zb == 0 && tid < 128) g[tid] = 0.f;
  }
}

// ---------------- fused GAT aggregate: TWO NODES PER WAVE -------------------
__global__ __launch_bounds__(256) void gat_gather_kernel(
    const int* __restrict__ cnt, const int* __restrict__ cpack,
    const float* __restrict__ table,
    const float* __restrict__ ssrc, const float* __restrict__ sdst,
    const unsigned short* __restrict__ hp, const float* __restrict__ bias,
    unsigned short* __restrict__ hout, int n) {
  __shared__ float exs[4][2][CAP];
  __shared__ int   srcs[4][2][CAP];
  const int wid = threadIdx.x >> 6, lane = threadIdx.x & 63;
  const int half = lane >> 5, hlane = lane & 31;
  const int node = ((blockIdx.x * blockDim.x + threadIdx.x) >> 6) * 2 + half;
  const bool valid = node < n;
  int deg = valid ? cnt[node] : 0;
  if (deg > CAP) deg = CAP;   // impossible for this graph; guards OOB
  const int j0 = node * CAP;
  const float sd = valid ? sdst[node] : 0.f;
  float den = 0.f, esum = 0.f;
  for (int k = hlane; k < deg; k += 32) {   // deg <= 64: at most 2 steps
    int pk_ = cpack[j0 + k];
    int s = pk_ >> 5;
    float t = table[pk_ & 31];
    float l = ssrc[s] + sd + t;
    l = (l > 0.f) ? l : NEG_SLOPE * l;
    float ex = expf(l);
    exs[wid][half][k] = ex; srcs[wid][half][k] = s * DD;
    den += ex; esum += t;
  }
#pragma unroll
  for (int off = 16; off; off >>= 1) {   // within-half butterfly
    den += __shfl_xor(den, off);
    esum += __shfl_xor(esum, off);
  }
  // self-loop (edge vector = mean of incoming -> table-space mean)
  float tl = esum / fmaxf((float)deg, 1.f);
  float ll = (valid ? ssrc[node] : 0.f) + sd + tl;
  ll = (ll > 0.f) ? ll : NEG_SLOPE * ll;
  float exl = expf(ll);
  den += exl;
  const float inv = 1.f / (den + 1e-16f);
  // pass 2: lane owns cols c..c+3 (one 8B uint2 of bf16 per row)
  const int c = hlane * 4;
  float a0, a1, a2, a3;
  {
    uint2 w = valid ? *(const uint2*)&hp[(size_t)node * DD + c] : make_uint2(0, 0);
    float a = exl * inv;
    a0 = a * bflo(w.x); a1 = a * bfhi(w.x);
    a2 = a * bflo(w.y); a3 = a * bfhi(w.y);
  }
  int k = 0;
  for (; k + 8 <= deg; k += 8) {
    uint2 w[8]; float a[8];
#pragma unroll
    for (int q = 0; q < 8; q++) {
      a[q] = exs[wid][half][k + q] * inv;
      w[q] = *(const uint2*)&hp[(size_t)(srcs[wid][half][k + q] + c)];
    }
#pragma unroll
    for (int q = 0; q < 8; q++) {
      a0 += a[q] * bflo(w[q].x); a1 += a[q] * bfhi(w[q].x);
      a2 += a[q] * bflo(w[q].y); a3 += a[q] * bfhi(w[q].y);
    }
  }
  for (; k + 4 <= deg; k += 4) {
    uint2 w[4]; float a[4];
#pragma unroll
    for (int q = 0; q < 4; q++) {
      a[q] = exs[wid][half][k + q] * inv;
      w[q] = *(const uint2*)&hp[(size_t)(srcs[wid][half][k + q] + c)];
    }
#pragma unroll
    for (int q = 0; q < 4; q++) {
      a0 += a[q] * bflo(w[q].x); a1 += a[q] * bfhi(w[q].x);
      a2 += a[q] * bflo(w[q].y); a3 += a[q] * bfhi(w[q].y);
    }
  }
  for (; k < deg; k++) {
    float aq = exs[wid][half][k] * inv;
    uint2 w = *(const uint2*)&hp[(size_t)(srcs[wid][half][k] + c)];
    a0 += aq * bflo(w.x); a1 += aq * bfhi(w.x);
    a2 += aq * bflo(w.y); a3 += aq * bfhi(w.y);
  }
  if (valid) {
    a0 = fmaxf(a0 + bias[c], 0.f);
    a1 = fmaxf(a1 + bias[c + 1], 0.f);
    a2 = fmaxf(a2 + bias[c + 2], 0.f);
    a3 = fmaxf(a3 + bias[c + 3], 0.f);
    uint2 o;
    o.x = (unsigned)f2bf(a0) | ((unsigned)f2bf(a1) << 16);
    o.y = (unsigned)f2bf(a2) | ((unsigned)f2bf(a3) << 16);
    *(uint2*)&hout[(size_t)node * DD + c] = o;
  }
}

__global__ void pool_kernel(const unsigned short* __restrict__ h, float* __restrict__ g, int n) {
  __shared__ float sh[128];
  int tid = threadIdx.x;
  int cp = tid & 63, half = tid >> 6;     // 4 row-groups, lane owns 2 cols
  float sx = 0.f, sy = 0.f;
  for (int r = blockIdx.x * 4 + half; r < n; r += gridDim.x * 4) {
    unsigned w = *(const unsigned*)&h[(size_t)r * DD + cp * 2];
    sx += bflo(w); sy += bfhi(w);
  }
  if (half == 0) { sh[cp * 2] = sx; sh[cp * 2 + 1] = sy; }
  __syncthreads();
  if (half == 1) { sh[cp * 2] += sx; sh[cp * 2 + 1] += sy; }
  __syncthreads();
  if (half == 2) { sh[cp * 2] += sx; sh[cp * 2 + 1] += sy; }
  __syncthreads();
  if (half == 3) {
    atomicAdd(&g[cp * 2], sh[cp * 2] + sx);
    atomicAdd(&g[cp * 2 + 1], sh[cp * 2 + 1] + sy);
  }
}

__global__ void readout_kernel(const float* __restrict__ g, const float* __restrict__ Wr1,
                               const float* __restrict__ br1, const float* __restrict__ Wr2,
                               const float* __restrict__ br2, float* __restrict__ out,
                               float inv_n) {
  __shared__ float gl[128];
  __shared__ float m[64];
  int t = threadIdx.x;  // 64 threads
  gl[t] = g[t] * inv_n;
  gl[t + 64] = g[t + 64] * inv_n;
  __syncthreads();
  {
    float acc = br1[t];
    for (int c = 0; c < 128; c++) acc += gl[c] * Wr1[c * 64 + t];
    m[t] = fmaxf(acc, 0.f);
  }
  __syncthreads();
  if (t < 32) {
    float acc = br2[t];
    for (int j = 0; j < 64; j++) acc += m[j] * Wr2[j * 32 + t];
    out[t] = acc;
  }
}

// ---------------- launch ----------------
extern "C" void kernel_launch(void* const* d_in, const int* in_sizes, int n_in,
                              void* d_out, int out_size, void* d_ws, size_t ws_size,
                              hipStream_t stream) {
  const float* x     = (const float*)d_in[0];
  const int*   ei    = (const int*)d_in[1];
  const int*   eattr = (const int*)d_in[2];
  const float* W1 = (const float*)d_in[3];
  const float* b1 = (const float*)d_in[4];
  const float* W2 = (const float*)d_in[5];
  const float* b2 = (const float*)d_in[6];
  const float* rel_emb = (const float*)d_in[7];
  const float* lin[2]      = {(const float*)d_in[8],  (const float*)d_in[14]};
  const float* att_src[2]  = {(const float*)d_in[9],  (const float*)d_in[15]};
  const float* att_dst[2]  = {(const float*)d_in[10], (const float*)d_in[16]};
  const float* att_edge[2] = {(const float*)d_in[11], (const float*)d_in[17]};
  const float* line[2]     = {(const float*)d_in[12], (const float*)d_in[18]};
  const float* bias[2]     = {(const float*)d_in[13], (const float*)d_in[19]};
  const float* Wr1 = (const float*)d_in[20];
  const float* br1 = (const float*)d_in[21];
  const float* Wr2 = (const float*)d_in[22];
  const float* br2 = (const float*)d_in[23];
  float* out = (float*)d_out;

  const int* srcv = ei;
  const int* dstv = ei + EE;

  char* wsb = (char*)d_ws;
  unsigned short* hA  = (unsigned short*)(wsb + 0);
  unsigned short* hp  = (unsigned short*)(wsb + 12900000);
  unsigned short* hB  = (unsigned short*)(wsb + 25900000);
  unsigned short* W1T   = (unsigned short*)(wsb + 64600000);
  unsigned short* W2L1T = (unsigned short*)(wsb + 64900000);   // [128][256] bf16
  unsigned short* lin2T = (unsigned short*)(wsb + 65040000);
  int* cnt     = (int*)(wsb + 65300008);                       // [50000]
  float* ssrc  = (float*)(wsb + 68100008);
  float* sdst  = (float*)(wsb + 68300008);
  float* tables = (float*)(wsb + 68502056);   // [2][32]
  float* g      = (float*)(wsb + 68502312);   // 128 f32
  float* b2l1   = (float*)(wsb + 68502824);   // 128 f32
  int* cpack    = (int*)(wsb + 70000000);     // [50000][64] = 12.8 MB

  dim3 blk(256);
  const int BKB = (EE + 255) / 256;   // 2344 bucket blocks

  // prep: weight transposes + tables + W2L1 + zero cnt/g  (966 blocks)
  prep_kernel<<<dim3(966), blk, 0, stream>>>(
      W1, W2, lin[0], lin[1], line[0], line[1], att_edge[0], att_edge[1],
      rel_emb, b2, W1T, W2L1T, lin2T, tables, b2l1, cnt, g);

  // fused encoder+layer1-lin (+ bucket CSR blocks backfilling idle CU slots)
  enc_fused<<<dim3(ENCB + BKB), blk, 0, stream>>>(
      x, W1T, b1, W2L1T, b2l1, att_src[0], att_dst[0], hp, ssrc, sdst,
      srcv, dstv, eattr, cnt, cpack);

  // layer 1 gather: hp -> hB
  gat_gather_kernel<<<dim3((NN / 2 * 64 + 255) / 256), blk, 0, stream>>>(
      cnt, cpack, tables, ssrc, sdst, hp, bias[0], hB, NN);
  // layer 2: hB -> (lin2+DOTS) hp,ssrc,sdst -> (gather) hA
  gemm_mfma<true, false, false, true><<<dim3(391, 1), blk, 0, stream>>>(
      hB, lin2T, nullptr, hp, NN, 128, 128, att_src[1], att_dst[1], ssrc, sdst);
  gat_gather_kernel<<<dim3((NN / 2 * 64 + 255) / 256), blk, 0, stream>>>(
      cnt, cpack, tables + 32, ssrc, sdst, hp, bias[1], hA, NN);

  pool_kernel<<<dim3(256), blk, 0, stream>>>(hA, g, NN);
  readout_kernel<<<1, 64, 0, stream>>>(g, Wr1, br1, Wr2, br2, out, 1.0f / NN);
}